// Round 12
// baseline (259.002 us; speedup 1.0000x reference)
//
#include <hip/hip_runtime.h>
#include <math.h>

#define S_LEN 2048
#define D_DIM 1024
#define NH 16
#define HD 64

typedef __attribute__((ext_vector_type(8))) short bf16x8;
typedef __attribute__((ext_vector_type(4))) float f32x4;

#define MFMA(a, b, c) __builtin_amdgcn_mfma_f32_16x16x32_bf16((a), (b), (c), 0, 0, 0)

__device__ __forceinline__ unsigned short f2bf(float x) {
    unsigned int u = __float_as_uint(x);
    u = (u + 0x7FFFu + ((u >> 16) & 1u)) >> 16;  // round-to-nearest-even
    return (unsigned short)u;
}
__device__ __forceinline__ float bf2f(unsigned short b) {
    return __uint_as_float(((unsigned int)b) << 16);
}
__device__ __forceinline__ void gl_lds16(const void* g, void* l) {
    __builtin_amdgcn_global_load_lds((const __attribute__((address_space(1))) unsigned int*)g,
                                     (__attribute__((address_space(3))) unsigned int*)l, 16, 0, 0);
}

// packed f32x2 -> bf16x2 (low = a, high = b).
#if defined(__has_builtin)
#if __has_builtin(__builtin_amdgcn_cvt_pk_bf16_f32)
#define HAVE_CVT_PK_BF16 1
#endif
#endif
__device__ __forceinline__ unsigned pack_bf16(float a, float b) {
#ifdef HAVE_CVT_PK_BF16
    auto r = __builtin_amdgcn_cvt_pk_bf16_f32(a, b);
    unsigned u;
    __builtin_memcpy(&u, &r, 4);
    return u;
#else
    unsigned ua = __float_as_uint(a) + 0x8000u;
    unsigned ub = __float_as_uint(b) + 0x8000u;
    return __builtin_amdgcn_perm(ub, ua, 0x07060302u);
#endif
}

// Tiled-swizzled layouts (identity-copy global_load_lds staging, 2-way LDS reads):
//   X/Oatt : [mblk=r>>7][kblk=k>>6][row=r&127][g=((k>>3)&7)^(r&7)][k&7]
//   Wqkv   : [head][kblk=d>>6][col=e][g=((d>>3)&7)^(e&7)][d&7]
//   Wo     : [nblk=n>>6][kblk=k>>6][col=n&63][g=((k>>3)&7)^(n&7)][k&7]

// ---------------------------------------------------------------------------
// prep (GATHER form): one thread = 8 contiguous output shorts (t = idx*8
// falls out of the layout bit-fields), so all writes are coalesced 16 B/lane.
// Wq folded scale = 0.125 * log2(e)  -> scores live in exp2 domain.
// grid: 4096 x 256 = 1M threads (X 512K; Wq/Wk/Wv/Wo 128K each)
// ---------------------------------------------------------------------------
__global__ __launch_bounds__(256) void prep(const float* __restrict__ GLO,
                                            const float* __restrict__ LOC,
                                            const float* __restrict__ Wq,
                                            const float* __restrict__ Wk,
                                            const float* __restrict__ Wv,
                                            const float* __restrict__ Wo,
                                            unsigned short* __restrict__ Xh,
                                            unsigned short* __restrict__ Xl,
                                            unsigned short* __restrict__ Wqh,
                                            unsigned short* __restrict__ Wql,
                                            unsigned short* __restrict__ Wkh,
                                            unsigned short* __restrict__ Wkl,
                                            unsigned short* __restrict__ Wvt,
                                            unsigned short* __restrict__ Wot) {
    int idx = blockIdx.x * 256 + threadIdx.x;  // 0 .. 1M-1
    if (idx < (1 << 19)) {
        // X: idx = mblk<<14 | kblk<<10 | row<<3 | gg ; t = idx*8
        int gg = idx & 7;
        int row = (idx >> 3) & 127;
        int kblk = (idx >> 10) & 15;
        int r = (idx >> 14) * 128 + row;  // 0..4095
        int kg = gg ^ (row & 7);
        const float* src = (r & 2048) ? LOC : GLO;
        const float* sp = src + (size_t)(r & 2047) * 1024 + kblk * 64 + kg * 8;
        float4 x0 = *(const float4*)sp;
        float4 x1 = *(const float4*)(sp + 4);
        size_t t = (size_t)idx * 8;
        ushort4 h0, l0, h1, l1;
        h0.x = f2bf(x0.x); l0.x = f2bf(x0.x - bf2f(h0.x));
        h0.y = f2bf(x0.y); l0.y = f2bf(x0.y - bf2f(h0.y));
        h0.z = f2bf(x0.z); l0.z = f2bf(x0.z - bf2f(h0.z));
        h0.w = f2bf(x0.w); l0.w = f2bf(x0.w - bf2f(h0.w));
        h1.x = f2bf(x1.x); l1.x = f2bf(x1.x - bf2f(h1.x));
        h1.y = f2bf(x1.y); l1.y = f2bf(x1.y - bf2f(h1.y));
        h1.z = f2bf(x1.z); l1.z = f2bf(x1.z - bf2f(h1.z));
        h1.w = f2bf(x1.w); l1.w = f2bf(x1.w - bf2f(h1.w));
        *(ushort4*)(Xh + t) = h0;
        *(ushort4*)(Xh + t + 4) = h1;
        *(ushort4*)(Xl + t) = l0;
        *(ushort4*)(Xl + t + 4) = l1;
    } else {
        int idx2 = idx - (1 << 19);
        int sec = idx2 >> 17;    // 0 Wq, 1 Wk, 2 Wv, 3 Wo
        int j = idx2 & 0x1FFFF;  // 128K per section
        size_t t = (size_t)j * 8;
        if (sec < 3) {
            // j = head<<13 | kblk<<9 | e<<3 | gg
            int gg = j & 7;
            int e = (j >> 3) & 63;
            int kblk = (j >> 9) & 15;
            int head = j >> 13;
            int kg = gg ^ (e & 7);
            int d0 = kblk * 64 + kg * 8;
            const float* W = (sec == 0) ? Wq : (sec == 1) ? Wk : Wv;
            const float* wp = W + (size_t)head * 65536 + (size_t)d0 * 64 + e;
            float wv8[8];
#pragma unroll
            for (int i = 0; i < 8; ++i) wv8[i] = wp[i * 64];
            if (sec == 0) {
                ushort4 h0, l0, h1, l1;
#pragma unroll
                for (int i = 0; i < 8; ++i) {
                    float v = wv8[i] * 0.18033688011112042f;  // 0.125 * log2(e)
                    unsigned short hi = f2bf(v);
                    unsigned short lo = f2bf(v - bf2f(hi));
                    if (i < 4) {
                        ((unsigned short*)&h0)[i] = hi;
                        ((unsigned short*)&l0)[i] = lo;
                    } else {
                        ((unsigned short*)&h1)[i - 4] = hi;
                        ((unsigned short*)&l1)[i - 4] = lo;
                    }
                }
                *(ushort4*)(Wqh + t) = h0;
                *(ushort4*)(Wqh + t + 4) = h1;
                *(ushort4*)(Wql + t) = l0;
                *(ushort4*)(Wql + t + 4) = l1;
            } else if (sec == 1) {
                ushort4 h0, l0, h1, l1;
#pragma unroll
                for (int i = 0; i < 8; ++i) {
                    float v = wv8[i];
                    unsigned short hi = f2bf(v);
                    unsigned short lo = f2bf(v - bf2f(hi));
                    if (i < 4) {
                        ((unsigned short*)&h0)[i] = hi;
                        ((unsigned short*)&l0)[i] = lo;
                    } else {
                        ((unsigned short*)&h1)[i - 4] = hi;
                        ((unsigned short*)&l1)[i - 4] = lo;
                    }
                }
                *(ushort4*)(Wkh + t) = h0;
                *(ushort4*)(Wkh + t + 4) = h1;
                *(ushort4*)(Wkl + t) = l0;
                *(ushort4*)(Wkl + t + 4) = l1;
            } else {
                ushort4 v0, v1;
#pragma unroll
                for (int i = 0; i < 8; ++i) {
                    unsigned short b = f2bf(wv8[i]);
                    if (i < 4)
                        ((unsigned short*)&v0)[i] = b;
                    else
                        ((unsigned short*)&v1)[i - 4] = b;
                }
                *(ushort4*)(Wvt + t) = v0;
                *(ushort4*)(Wvt + t + 4) = v1;
            }
        } else {
            // j = nblk<<13 | kblk<<9 | col<<3 | gg
            int gg = j & 7;
            int col = (j >> 3) & 63;
            int kblk = (j >> 9) & 15;
            int nblk = j >> 13;
            int kg = gg ^ (col & 7);
            int k0 = kblk * 64 + kg * 8;
            int n = nblk * 64 + col;
            ushort4 v0, v1;
#pragma unroll
            for (int i = 0; i < 8; ++i) {
                unsigned short b = f2bf(Wo[(size_t)(k0 + i) * 1024 + n]);
                if (i < 4)
                    ((unsigned short*)&v0)[i] = b;
                else
                    ((unsigned short*)&v1)[i - 4] = b;
            }
            *(ushort4*)(Wot + t) = v0;
            *(ushort4*)(Wot + t + 4) = v1;
        }
    }
}

// ---------------------------------------------------------------------------
// qkv_proj: staged-LDS GEMM, 7 MFMA passes share staged A/B (round-10 form).
// grid: mblk(32) x head(16) = 512 blocks
// ---------------------------------------------------------------------------
__global__ __launch_bounds__(256) void qkv_proj(const unsigned short* __restrict__ Xh,
                                                const unsigned short* __restrict__ Xl,
                                                const unsigned short* __restrict__ Wqh,
                                                const unsigned short* __restrict__ Wql,
                                                const unsigned short* __restrict__ Wkh,
                                                const unsigned short* __restrict__ Wkl,
                                                const unsigned short* __restrict__ Wvt,
                                                unsigned short* __restrict__ Qh,
                                                unsigned short* __restrict__ Ql,
                                                unsigned short* __restrict__ Kh,
                                                unsigned short* __restrict__ Kl,
                                                unsigned short* __restrict__ Vt) {
    __shared__ unsigned short lds[36864];
    const int bid = blockIdx.x;
    const int mblk = bid & 31;
    const int head = bid >> 5;
    const int tid = threadIdx.x;
    const int lane = tid & 63;
    const int w = tid >> 6;
    const int l15 = lane & 15, quad = lane >> 4;

    f32x4 aq[2][4] = {}, ak[2][4] = {}, av[2][4] = {};
    const size_t abase0 = (size_t)mblk * 131072;
    const size_t bbase0 = (size_t)head * 65536;

    for (int kb = 0; kb < 16; ++kb) {
        __syncthreads();
        {
            const size_t ab = abase0 + (size_t)kb * 8192;
            const size_t bb = bbase0 + (size_t)kb * 4096;
#pragma unroll
            for (int j = 0; j < 4; ++j) {
                int seg = j * 256 + tid;
                gl_lds16(Xh + ab + seg * 8, &lds[seg * 8]);
                gl_lds16(Xl + ab + seg * 8, &lds[8192 + seg * 8]);
            }
#pragma unroll
            for (int j = 0; j < 2; ++j) {
                int seg = j * 256 + tid;
                gl_lds16(Wqh + bb + seg * 8, &lds[16384 + seg * 8]);
                gl_lds16(Wql + bb + seg * 8, &lds[20480 + seg * 8]);
                gl_lds16(Wkh + bb + seg * 8, &lds[24576 + seg * 8]);
                gl_lds16(Wkl + bb + seg * 8, &lds[28672 + seg * 8]);
                gl_lds16(Wvt + bb + seg * 8, &lds[32768 + seg * 8]);
            }
        }
        __syncthreads();

#pragma unroll
        for (int ksub = 0; ksub < 2; ++ksub) {
            bf16x8 ah[2], al8[2];
#pragma unroll
            for (int mt = 0; mt < 2; ++mt) {
                int row = w * 32 + mt * 16 + l15;
                int g = (ksub * 4 + quad) ^ (row & 7);
                ah[mt] = *(const bf16x8*)&lds[row * 64 + g * 8];
                al8[mt] = *(const bf16x8*)&lds[8192 + row * 64 + g * 8];
            }
#pragma unroll
            for (int nt = 0; nt < 4; ++nt) {
                int col = nt * 16 + l15;
                int o = col * 64 + ((ksub * 4 + quad) ^ (col & 7)) * 8;
                bf16x8 bqh = *(const bf16x8*)&lds[16384 + o];
                bf16x8 bql = *(const bf16x8*)&lds[20480 + o];
                bf16x8 bkh = *(const bf16x8*)&lds[24576 + o];
                bf16x8 bkl = *(const bf16x8*)&lds[28672 + o];
                bf16x8 bv = *(const bf16x8*)&lds[32768 + o];
#pragma unroll
                for (int mt = 0; mt < 2; ++mt) {
                    f32x4 a = aq[mt][nt];
                    a = MFMA(ah[mt], bqh, a);
                    a = MFMA(ah[mt], bql, a);
                    a = MFMA(al8[mt], bqh, a);
                    aq[mt][nt] = a;
                    f32x4 b = ak[mt][nt];
                    b = MFMA(ah[mt], bkh, b);
                    b = MFMA(ah[mt], bkl, b);
                    b = MFMA(al8[mt], bkh, b);
                    ak[mt][nt] = b;
                    av[mt][nt] = MFMA(ah[mt], bv, av[mt][nt]);
                }
            }
        }
    }

#pragma unroll
    for (int mt = 0; mt < 2; ++mt) {
        const int rbase = mblk * 128 + w * 32 + mt * 16 + quad * 4;
#pragma unroll
        for (int nt = 0; nt < 4; ++nt) {
            const int col = head * 64 + nt * 16 + l15;
#pragma unroll
            for (int r = 0; r < 4; ++r) {
                size_t a = (size_t)(rbase + r) * D_DIM + col;
                float vq = aq[mt][nt][r];
                unsigned short hq = f2bf(vq);
                Qh[a] = hq;
                Ql[a] = f2bf(vq - bf2f(hq));
                float vk = ak[mt][nt][r];
                unsigned short hk = f2bf(vk);
                Kh[a] = hk;
                Kl[a] = f2bf(vk - bf2f(hk));
            }
            ushort4 vp;
            vp.x = f2bf(av[mt][nt][0]);
            vp.y = f2bf(av[mt][nt][1]);
            vp.z = f2bf(av[mt][nt][2]);
            vp.w = f2bf(av[mt][nt][3]);
            *(ushort4*)(Vt + (size_t)col * (2 * S_LEN) + rbase) = vp;
        }
    }
}

// ---------------------------------------------------------------------------
// attn: flash attention, S^T = K.Q^T.  Round-25: 32 q/wave at 12 waves/CU.
// Ledger: R6 = 95.5us @16 waves (16q); R11 = 103us @8 waves (32q, 1 blk/CU
// because the ~155-reg state allows only 3 waves/EU with 8-wave blocks).
// Fix: 4-wave (256-thr) blocks quantize residency finer: (256,3) -> 3
// blocks/CU = 12 waves/CU, VGPR cap 512/3 ~ 170 >= state (~155, no spill).
// LDS fits via SPLIT-P: per mt write keys 0-31 (1 KB/wave, R5-verified
// 32-key addressing), PV c=0, overwrite with keys 32-63, PV c=1 (same-wave
// LDS ordering makes the overwrite safe).  LDS = 48 KB staging + 4 KB P =
// 52 KB -> 3 blocks/CU.  All else identical to R11 (passed).
// grid: qblk(16) x khalf(2) x dir(2) x head(16) = 1024 blocks x 256 thr
// ---------------------------------------------------------------------------
__global__ __launch_bounds__(256, 3) void attn_kernel(const unsigned short* __restrict__ Qh_,
                                                      const unsigned short* __restrict__ Ql_,
                                                      const unsigned short* __restrict__ Kh_,
                                                      const unsigned short* __restrict__ Kl_,
                                                      const unsigned short* __restrict__ Vt_,
                                                      unsigned short* __restrict__ Opart,
                                                      float* __restrict__ Lse) {
    // shorts: buf0 Kh[0,4096) Kl[4096,8192) V[8192,12288); buf1 +12288;
    // P 24576 + w*512 (4 waves x 1 KB).  Total 26624 shorts = 52 KB.
    __shared__ unsigned short lds[26624];
    const int bid = blockIdx.x;
    // XCD panel swizzle: low 6 bits = (khalf,dir,head) panel id; qblk high.
    const int head = bid & 15;
    const int dir = (bid >> 4) & 1;
    const int khalf = (bid >> 5) & 1;
    const int qblk = bid >> 6;  // 0..15
    const int src_q = dir, src_kv = 1 - dir;

    const int tid = threadIdx.x;  // 0..255
    const int lane = tid & 63;
    const int w = tid >> 6;  // 0..3
    const int l15 = lane & 15, quad = lane >> 4;
    const int q0w = qblk * 128 + w * 32;

    const unsigned short* KhB0 =
        Kh_ + (size_t)(src_kv * S_LEN + khalf * 1024) * D_DIM + head * 64;
    const unsigned short* KlB0 =
        Kl_ + (size_t)(src_kv * S_LEN + khalf * 1024) * D_DIM + head * 64;
    const unsigned short* Vtp =
        Vt_ + (size_t)(head * 64) * (2 * S_LEN) + src_kv * S_LEN + khalf * 1024;

    auto stage = [&](int k0, int boff) {
#pragma unroll
        for (int j = 0; j < 2; ++j) {
            int i = j * 256 + tid;  // 512 segs per 64x64 tile
            int sr = i >> 3;
            int sc = ((i & 7) ^ (sr & 7)) * 8;
            gl_lds16(KhB0 + (size_t)(k0 + sr) * D_DIM + sc, &lds[boff + i * 8]);
            gl_lds16(KlB0 + (size_t)(k0 + sr) * D_DIM + sc, &lds[boff + 4096 + i * 8]);
            gl_lds16(Vtp + (size_t)sr * (2 * S_LEN) + k0 + sc, &lds[boff + 8192 + i * 8]);
        }
    };

    // Q fragments (B-operand): B[k=e][n=q], lane n=l15, k=quad*8+j (+c*32)
    bf16x8 qh[2][2], ql[2][2];
#pragma unroll
    for (int mt = 0; mt < 2; ++mt) {
        const size_t qrow =
            (size_t)(src_q * S_LEN + q0w + mt * 16 + l15) * D_DIM + head * 64 + quad * 8;
#pragma unroll
        for (int c = 0; c < 2; ++c) {
            qh[mt][c] = *(const bf16x8*)(Qh_ + qrow + c * 32);
            ql[mt][c] = *(const bf16x8*)(Ql_ + qrow + c * 32);
        }
    }

    f32x4 o[2][4] = {};  // out^T tiles: [mt][et]; lane: q=l15, e=quad*4+r
    float mi[2] = {-1e30f, -1e30f};
    float lip[2] = {0.f, 0.f};  // per-lane li partials (16 keys/chunk each)
    unsigned short* Pw = lds + 24576 + w * 512;

    auto chunk = [&](int kb) {
        // S^T tiles: sa[mt][kt], keys kt*16+quad*4+r, q = l15 (3-pass split-bf16)
        f32x4 sa[2][4];
#pragma unroll
        for (int kt = 0; kt < 4; ++kt) {
            const int row = kt * 16 + l15;
            const int s0 = (quad ^ (row & 7)) * 8;
            const int s1 = ((4 + quad) ^ (row & 7)) * 8;
            bf16x8 kh0 = *(const bf16x8*)&lds[kb + row * 64 + s0];
            bf16x8 kh1 = *(const bf16x8*)&lds[kb + row * 64 + s1];
            bf16x8 kl0 = *(const bf16x8*)&lds[kb + 4096 + row * 64 + s0];
            bf16x8 kl1 = *(const bf16x8*)&lds[kb + 4096 + row * 64 + s1];
#pragma unroll
            for (int mt = 0; mt < 2; ++mt) {
                f32x4 a = {};
                a = MFMA(kh0, qh[mt][0], a);
                a = MFMA(kh1, qh[mt][1], a);
                a = MFMA(kl0, qh[mt][0], a);
                a = MFMA(kl1, qh[mt][1], a);
                a = MFMA(kh0, ql[mt][0], a);
                a = MFMA(kh1, ql[mt][1], a);
                sa[mt][kt] = a;
            }
        }

        // per m-tile: online softmax (exp2 domain, defer-max THR=8) + PV
#pragma unroll
        for (int mt = 0; mt < 2; ++mt) {
            f32x4 t4 = __builtin_elementwise_max(__builtin_elementwise_max(sa[mt][0], sa[mt][1]),
                                                 __builtin_elementwise_max(sa[mt][2], sa[mt][3]));
            float tm = fmaxf(fmaxf(t4[0], t4[1]), fmaxf(t4[2], t4[3]));
            tm = fmaxf(tm, __shfl_xor(tm, 16, 64));
            tm = fmaxf(tm, __shfl_xor(tm, 32, 64));
            if (__ballot(tm > mi[mt] + 8.f)) {  // rescale only on >8 max growth (T13)
                float mn = fmaxf(mi[mt], tm);
                float al = exp2f(mi[mt] - mn);
                mi[mt] = mn;
                lip[mt] *= al;
                const f32x4 alv = {al, al, al, al};
#pragma unroll
                for (int et = 0; et < 4; ++et) o[mt][et] *= alv;
            }
            const float mn = mi[mt];
            const f32x4 mnv = {mn, mn, mn, mn};
            f32x4 rs4 = {};
            // SPLIT-P: two 32-key halves share a 1 KB/wave P buffer.
#pragma unroll
            for (int c = 0; c < 2; ++c) {
#pragma unroll
                for (int k2 = 0; k2 < 2; ++k2) {
                    const int kt = c * 2 + k2;
                    f32x4 p = sa[mt][kt] - mnv;
#pragma unroll
                    for (int r = 0; r < 4; ++r) p[r] = exp2f(p[r]);
                    rs4 += p;
                    uint2 pk;
                    pk.x = pack_bf16(p[0], p[1]);
                    pk.y = pack_bf16(p[2], p[3]);
                    int g = (k2 * 2 + (quad >> 1)) ^ (l15 & 3);  // R5-verified 32-key layout
                    *(uint2*)&Pw[l15 * 32 + g * 8 + (quad & 1) * 4] = pk;
                }
                bf16x8 pf = *(const bf16x8*)&Pw[l15 * 32 + ((quad ^ (l15 & 3)) * 8)];
#pragma unroll
                for (int et = 0; et < 4; ++et) {
                    const int row = et * 16 + l15;
                    const int sl = ((c * 4 + quad) ^ (row & 7)) * 8;
                    bf16x8 vf = *(const bf16x8*)&lds[kb + 8192 + row * 64 + sl];
                    o[mt][et] = MFMA(vf, pf, o[mt][et]);
                }
            }
            lip[mt] += (rs4[0] + rs4[1]) + (rs4[2] + rs4[3]);
        }
    };

    stage(0, 0);
#pragma unroll 1
    for (int kd = 0; kd < 16; kd += 2) {
        __syncthreads();  // buf0 (chunk kd) ready; all waves done reading buf1
        if (kd + 1 < 16) stage((kd + 1) * 64, 12288);
        chunk(0);
        __syncthreads();  // buf1 (chunk kd+1) ready; all waves done reading buf0
        if (kd + 2 < 16) stage((kd + 2) * 64, 0);
        chunk(12288);
    }

    // epilogue: reduce li across the quad group; store NORMALIZED bf16
    // partial + per-row LSE (exp2 domain) for the combine pass (R4 layout).
    const size_t pbase = (size_t)(khalf * 32 + dir * 16 + head) * 2048;
#pragma unroll
    for (int mt = 0; mt < 2; ++mt) {
        float lq = lip[mt];
        lq += __shfl_xor(lq, 16, 64);
        lq += __shfl_xor(lq, 32, 64);
        const float rl = __builtin_amdgcn_rcpf(lq);
        const int q = q0w + mt * 16 + l15;
        const size_t ob = (pbase + q) * 64;
#pragma unroll
        for (int et = 0; et < 4; ++et) {
            ushort4 pk;
            pk.x = f2bf(o[mt][et][0] * rl);
            pk.y = f2bf(o[mt][et][1] * rl);
            pk.z = f2bf(o[mt][et][2] * rl);
            pk.w = f2bf(o[mt][et][3] * rl);
            *(ushort4*)(Opart + ob + et * 16 + quad * 4) = pk;
        }
        if (quad == 0) Lse[pbase + q] = mi[mt] + __log2f(lq);
    }
}

// ---------------------------------------------------------------------------
// combine: merge the two key-half partials into tiled bf16 Oatt (R4 form,
// verified).  thread = 8 contiguous e of one (dh,q) row; reads coalesced
// 16 B/lane, writes one 16 B tiled segment.  grid: 2048 x 256.
// ---------------------------------------------------------------------------
__global__ __launch_bounds__(256) void combine(const unsigned short* __restrict__ Opart,
                                               const float* __restrict__ Lse,
                                               unsigned short* __restrict__ Oatt) {
    const int t = blockIdx.x * 256 + threadIdx.x;  // 0 .. 524287
    const int qi = t >> 3;                         // dh(5b) | q(11b)
    const int e0 = (t & 7) * 8;
    const int dh = qi >> 11;
    const int q = qi & 2047;

    const size_t row1 = (size_t)dh * 2048 + q;
    const size_t b1 = row1 * 64 + e0;
    const size_t b2 = b1 + (size_t)4194304;  // + 32*2048*64 (khalf 1)
    ushort4 p1a = *(const ushort4*)(Opart + b1);
    ushort4 p1b = *(const ushort4*)(Opart + b1 + 4);
    ushort4 p2a = *(const ushort4*)(Opart + b2);
    ushort4 p2b = *(const ushort4*)(Opart + b2 + 4);
    const float l1 = Lse[row1];
    const float l2 = Lse[row1 + 65536];

    const float M = fmaxf(l1, l2);
    float w1 = exp2f(l1 - M);
    float w2 = exp2f(l2 - M);
    const float rw = __builtin_amdgcn_rcpf(w1 + w2);
    w1 *= rw;
    w2 *= rw;

    ushort4 oa, ob;
    oa.x = f2bf(bf2f(p1a.x) * w1 + bf2f(p2a.x) * w2);
    oa.y = f2bf(bf2f(p1a.y) * w1 + bf2f(p2a.y) * w2);
    oa.z = f2bf(bf2f(p1a.z) * w1 + bf2f(p2a.z) * w2);
    oa.w = f2bf(bf2f(p1a.w) * w1 + bf2f(p2a.w) * w2);
    ob.x = f2bf(bf2f(p1b.x) * w1 + bf2f(p2b.x) * w2);
    ob.y = f2bf(bf2f(p1b.y) * w1 + bf2f(p2b.y) * w2);
    ob.z = f2bf(bf2f(p1b.z) * w1 + bf2f(p2b.z) * w2);
    ob.w = f2bf(bf2f(p1b.w) * w1 + bf2f(p2b.w) * w2);

    const int rowit = q >> 4;
    const int g = ((e0 >> 3) ^ (rowit & 7)) & 7;
    const size_t oaddr =
        (size_t)dh * 131072 + (size_t)(q & 15) * 8192 + (size_t)rowit * 64 + g * 8;
    *(ushort4*)(Oatt + oaddr) = oa;
    *(ushort4*)(Oatt + oaddr + 4) = ob;
}

// ---------------------------------------------------------------------------
// oproj: out = view @ Wo, staged-LDS GEMM, double-buffered prefetch.
// XCD relabel: mblk in LOW bits -> A-panel (Oatt) sharers at stride-32 bids
// = one XCD; per-XCD working set (4 A-panels + all B) ~3 MB = L2-resident.
// grid: nblk(16) x mblk(32) = 512 blocks
// ---------------------------------------------------------------------------
__global__ __launch_bounds__(256) void oproj(const unsigned short* __restrict__ Oatt,
                                             const unsigned short* __restrict__ Wot,
                                             float* __restrict__ out) {
    __shared__ unsigned short lds[24576];  // buf: A 8192 + B 4096; x2
    const int bid = blockIdx.x;
    const int mblk = bid & 31;
    const int nblk = bid >> 5;
    const int tid = threadIdx.x;
    const int lane = tid & 63, w = tid >> 6, l15 = lane & 15, quad = lane >> 4;

    f32x4 acc[2][4] = {};
    const size_t abase = (size_t)mblk * 131072;
    const size_t bbase = (size_t)nblk * 65536;

    auto ostage = [&](int kb, int boff) {
#pragma unroll
        for (int j = 0; j < 4; ++j) {
            int seg = j * 256 + tid;
            gl_lds16(Oatt + abase + (size_t)kb * 8192 + seg * 8, &lds[boff + seg * 8]);
        }
#pragma unroll
        for (int j = 0; j < 2; ++j) {
            int seg = j * 256 + tid;
            gl_lds16(Wot + bbase + (size_t)kb * 4096 + seg * 8, &lds[boff + 8192 + seg * 8]);
        }
    };

    auto compute = [&](int boff) {
#pragma unroll
        for (int ksub = 0; ksub < 2; ++ksub) {
            bf16x8 a[2];
#pragma unroll
            for (int mt = 0; mt < 2; ++mt) {
                int row = w * 32 + mt * 16 + l15;
                a[mt] =
                    *(const bf16x8*)&lds[boff + row * 64 + (((ksub * 4 + quad) ^ (row & 7)) * 8)];
            }
#pragma unroll
            for (int nt = 0; nt < 4; ++nt) {
                int col = nt * 16 + l15;
                bf16x8 b = *(const bf16x8*)&lds[boff + 8192 + col * 64 +
                                                (((ksub * 4 + quad) ^ (col & 7)) * 8)];
#pragma unroll
                for (int mt = 0; mt < 2; ++mt) acc[mt][nt] = MFMA(a[mt], b, acc[mt][nt]);
            }
        }
    };

    ostage(0, 0);
#pragma unroll 1
    for (int kb = 0; kb < 16; kb += 2) {
        __syncthreads();
        if (kb + 1 < 16) ostage(kb + 1, 12288);
        compute(0);
        __syncthreads();
        if (kb + 2 < 16) ostage(kb + 2, 0);
        compute(12288);
    }

#pragma unroll
    for (int mt = 0; mt < 2; ++mt) {
        const int rbase = mblk * 128 + w * 32 + mt * 16 + quad * 4;
#pragma unroll
        for (int nt = 0; nt < 4; ++nt)
#pragma unroll
            for (int r = 0; r < 4; ++r)
                out[(size_t)(rbase + r) * D_DIM + nblk * 64 + nt * 16 + l15] = acc[mt][nt][r];
    }
}

// ---------------------------------------------------------------------------
extern "C" void kernel_launch(void* const* d_in, const int* in_sizes, int n_in, void* d_out,
                              int out_size, void* d_ws, size_t ws_size, hipStream_t stream) {
    const float* GLO = (const float*)d_in[0];
    const float* LOC = (const float*)d_in[1];
    const float* Wq = (const float*)d_in[2];
    const float* Wk = (const float*)d_in[3];
    const float* Wv = (const float*)d_in[4];
    const float* Wo = (const float*)d_in[5];
    float* out = (float*)d_out;

    unsigned short* ws = (unsigned short*)d_ws;
    unsigned short* Xh = ws + 0;
    unsigned short* Xl = ws + 4194304;
    unsigned short* Wqh = ws + 8388608;
    unsigned short* Wql = ws + 9437184;
    unsigned short* Wkh = ws + 10485760;
    unsigned short* Wkl = ws + 11534336;
    unsigned short* Wvt = ws + 12582912;
    unsigned short* Wot = ws + 13631488;
    unsigned short* Qh = ws + 14680064;
    unsigned short* Ql = ws + 18874368;
    unsigned short* Kh = ws + 23068672;
    unsigned short* Kl = ws + 27262976;
    unsigned short* Vt = ws + 31457280;
    unsigned short* Oatt = ws + 35651584;
    // Partial buffers OVERLAY regions dead after qkv_proj (R4-verified):
    //   Opart (8,388,608 shorts) = Xh+Xl region; Lse (131,072 f32) = Wqh region.
    // Total ws footprint unchanged (79.7 MB).
    unsigned short* Opart = ws + 0;
    float* LseP = (float*)(ws + 8388608);

    prep<<<4096, 256, 0, stream>>>(GLO, LOC, Wq, Wk, Wv, Wo, Xh, Xl, Wqh, Wql, Wkh, Wkl, Wvt, Wot);
    qkv_proj<<<512, 256, 0, stream>>>(Xh, Xl, Wqh, Wql, Wkh, Wkl, Wvt, Qh, Ql, Kh, Kl, Vt);
    attn_kernel<<<1024, 256, 0, stream>>>(Qh, Ql, Kh, Kl, Vt, Opart, LseP);
    combine<<<2048, 256, 0, stream>>>(Opart, LseP, Oatt);
    oproj<<<512, 256, 0, stream>>>(Oatt, Wot, out);
}

// Round 13
// 236.887 us; speedup vs baseline: 1.0934x; 1.0934x over previous
//
#include <hip/hip_runtime.h>
#include <math.h>

#define S_LEN 2048
#define D_DIM 1024
#define NH 16
#define HD 64

typedef __attribute__((ext_vector_type(8))) short bf16x8;
typedef __attribute__((ext_vector_type(4))) float f32x4;

#define MFMA(a, b, c) __builtin_amdgcn_mfma_f32_16x16x32_bf16((a), (b), (c), 0, 0, 0)

__device__ __forceinline__ unsigned short f2bf(float x) {
    unsigned int u = __float_as_uint(x);
    u = (u + 0x7FFFu + ((u >> 16) & 1u)) >> 16;  // round-to-nearest-even
    return (unsigned short)u;
}
__device__ __forceinline__ float bf2f(unsigned short b) {
    return __uint_as_float(((unsigned int)b) << 16);
}
__device__ __forceinline__ void gl_lds16(const void* g, void* l) {
    __builtin_amdgcn_global_load_lds((const __attribute__((address_space(1))) unsigned int*)g,
                                     (__attribute__((address_space(3))) unsigned int*)l, 16, 0, 0);
}

// packed f32x2 -> bf16x2 (low = a, high = b).
#if defined(__has_builtin)
#if __has_builtin(__builtin_amdgcn_cvt_pk_bf16_f32)
#define HAVE_CVT_PK_BF16 1
#endif
#endif
__device__ __forceinline__ unsigned pack_bf16(float a, float b) {
#ifdef HAVE_CVT_PK_BF16
    auto r = __builtin_amdgcn_cvt_pk_bf16_f32(a, b);
    unsigned u;
    __builtin_memcpy(&u, &r, 4);
    return u;
#else
    unsigned ua = __float_as_uint(a) + 0x8000u;
    unsigned ub = __float_as_uint(b) + 0x8000u;
    return __builtin_amdgcn_perm(ub, ua, 0x07060302u);
#endif
}

// Tiled-swizzled layouts (identity-copy global_load_lds staging, 2-way LDS reads):
//   X/Oatt : [mblk=r>>7][kblk=k>>6][row=r&127][g=((k>>3)&7)^(r&7)][k&7]
//   Wqkv   : [head][kblk=d>>6][col=e][g=((d>>3)&7)^(e&7)][d&7]
//   Wo     : [nblk=n>>6][kblk=k>>6][col=n&63][g=((k>>3)&7)^(n&7)][k&7]

// ---------------------------------------------------------------------------
// prep (GATHER form): one thread = 8 contiguous output shorts (t = idx*8
// falls out of the layout bit-fields), so all writes are coalesced 16 B/lane.
// Wq folded scale = 0.125 * log2(e)  -> scores live in exp2 domain.
// grid: 4096 x 256 = 1M threads (X 512K; Wq/Wk/Wv/Wo 128K each)
// ---------------------------------------------------------------------------
__global__ __launch_bounds__(256) void prep(const float* __restrict__ GLO,
                                            const float* __restrict__ LOC,
                                            const float* __restrict__ Wq,
                                            const float* __restrict__ Wk,
                                            const float* __restrict__ Wv,
                                            const float* __restrict__ Wo,
                                            unsigned short* __restrict__ Xh,
                                            unsigned short* __restrict__ Xl,
                                            unsigned short* __restrict__ Wqh,
                                            unsigned short* __restrict__ Wql,
                                            unsigned short* __restrict__ Wkh,
                                            unsigned short* __restrict__ Wkl,
                                            unsigned short* __restrict__ Wvt,
                                            unsigned short* __restrict__ Wot) {
    int idx = blockIdx.x * 256 + threadIdx.x;  // 0 .. 1M-1
    if (idx < (1 << 19)) {
        // X: idx = mblk<<14 | kblk<<10 | row<<3 | gg ; t = idx*8
        int gg = idx & 7;
        int row = (idx >> 3) & 127;
        int kblk = (idx >> 10) & 15;
        int r = (idx >> 14) * 128 + row;  // 0..4095
        int kg = gg ^ (row & 7);
        const float* src = (r & 2048) ? LOC : GLO;
        const float* sp = src + (size_t)(r & 2047) * 1024 + kblk * 64 + kg * 8;
        float4 x0 = *(const float4*)sp;
        float4 x1 = *(const float4*)(sp + 4);
        size_t t = (size_t)idx * 8;
        ushort4 h0, l0, h1, l1;
        h0.x = f2bf(x0.x); l0.x = f2bf(x0.x - bf2f(h0.x));
        h0.y = f2bf(x0.y); l0.y = f2bf(x0.y - bf2f(h0.y));
        h0.z = f2bf(x0.z); l0.z = f2bf(x0.z - bf2f(h0.z));
        h0.w = f2bf(x0.w); l0.w = f2bf(x0.w - bf2f(h0.w));
        h1.x = f2bf(x1.x); l1.x = f2bf(x1.x - bf2f(h1.x));
        h1.y = f2bf(x1.y); l1.y = f2bf(x1.y - bf2f(h1.y));
        h1.z = f2bf(x1.z); l1.z = f2bf(x1.z - bf2f(h1.z));
        h1.w = f2bf(x1.w); l1.w = f2bf(x1.w - bf2f(h1.w));
        *(ushort4*)(Xh + t) = h0;
        *(ushort4*)(Xh + t + 4) = h1;
        *(ushort4*)(Xl + t) = l0;
        *(ushort4*)(Xl + t + 4) = l1;
    } else {
        int idx2 = idx - (1 << 19);
        int sec = idx2 >> 17;    // 0 Wq, 1 Wk, 2 Wv, 3 Wo
        int j = idx2 & 0x1FFFF;  // 128K per section
        size_t t = (size_t)j * 8;
        if (sec < 3) {
            // j = head<<13 | kblk<<9 | e<<3 | gg
            int gg = j & 7;
            int e = (j >> 3) & 63;
            int kblk = (j >> 9) & 15;
            int head = j >> 13;
            int kg = gg ^ (e & 7);
            int d0 = kblk * 64 + kg * 8;
            const float* W = (sec == 0) ? Wq : (sec == 1) ? Wk : Wv;
            const float* wp = W + (size_t)head * 65536 + (size_t)d0 * 64 + e;
            float wv8[8];
#pragma unroll
            for (int i = 0; i < 8; ++i) wv8[i] = wp[i * 64];
            if (sec == 0) {
                ushort4 h0, l0, h1, l1;
#pragma unroll
                for (int i = 0; i < 8; ++i) {
                    float v = wv8[i] * 0.18033688011112042f;  // 0.125 * log2(e)
                    unsigned short hi = f2bf(v);
                    unsigned short lo = f2bf(v - bf2f(hi));
                    if (i < 4) {
                        ((unsigned short*)&h0)[i] = hi;
                        ((unsigned short*)&l0)[i] = lo;
                    } else {
                        ((unsigned short*)&h1)[i - 4] = hi;
                        ((unsigned short*)&l1)[i - 4] = lo;
                    }
                }
                *(ushort4*)(Wqh + t) = h0;
                *(ushort4*)(Wqh + t + 4) = h1;
                *(ushort4*)(Wql + t) = l0;
                *(ushort4*)(Wql + t + 4) = l1;
            } else if (sec == 1) {
                ushort4 h0, l0, h1, l1;
#pragma unroll
                for (int i = 0; i < 8; ++i) {
                    float v = wv8[i];
                    unsigned short hi = f2bf(v);
                    unsigned short lo = f2bf(v - bf2f(hi));
                    if (i < 4) {
                        ((unsigned short*)&h0)[i] = hi;
                        ((unsigned short*)&l0)[i] = lo;
                    } else {
                        ((unsigned short*)&h1)[i - 4] = hi;
                        ((unsigned short*)&l1)[i - 4] = lo;
                    }
                }
                *(ushort4*)(Wkh + t) = h0;
                *(ushort4*)(Wkh + t + 4) = h1;
                *(ushort4*)(Wkl + t) = l0;
                *(ushort4*)(Wkl + t + 4) = l1;
            } else {
                ushort4 v0, v1;
#pragma unroll
                for (int i = 0; i < 8; ++i) {
                    unsigned short b = f2bf(wv8[i]);
                    if (i < 4)
                        ((unsigned short*)&v0)[i] = b;
                    else
                        ((unsigned short*)&v1)[i - 4] = b;
                }
                *(ushort4*)(Wvt + t) = v0;
                *(ushort4*)(Wvt + t + 4) = v1;
            }
        } else {
            // j = nblk<<13 | kblk<<9 | col<<3 | gg
            int gg = j & 7;
            int col = (j >> 3) & 63;
            int kblk = (j >> 9) & 15;
            int nblk = j >> 13;
            int kg = gg ^ (col & 7);
            int k0 = kblk * 64 + kg * 8;
            int n = nblk * 64 + col;
            ushort4 v0, v1;
#pragma unroll
            for (int i = 0; i < 8; ++i) {
                unsigned short b = f2bf(Wo[(size_t)(k0 + i) * 1024 + n]);
                if (i < 4)
                    ((unsigned short*)&v0)[i] = b;
                else
                    ((unsigned short*)&v1)[i - 4] = b;
            }
            *(ushort4*)(Wot + t) = v0;
            *(ushort4*)(Wot + t + 4) = v1;
        }
    }
}

// ---------------------------------------------------------------------------
// qkv_proj: staged-LDS GEMM, 7 MFMA passes share staged A/B (round-10 form).
// A-panel sharers (same mblk) already sit at stride-32 bids -> same XCD.
// grid: mblk(32) x head(16) = 512 blocks
// ---------------------------------------------------------------------------
__global__ __launch_bounds__(256) void qkv_proj(const unsigned short* __restrict__ Xh,
                                                const unsigned short* __restrict__ Xl,
                                                const unsigned short* __restrict__ Wqh,
                                                const unsigned short* __restrict__ Wql,
                                                const unsigned short* __restrict__ Wkh,
                                                const unsigned short* __restrict__ Wkl,
                                                const unsigned short* __restrict__ Wvt,
                                                unsigned short* __restrict__ Qh,
                                                unsigned short* __restrict__ Ql,
                                                unsigned short* __restrict__ Kh,
                                                unsigned short* __restrict__ Kl,
                                                unsigned short* __restrict__ Vt) {
    __shared__ unsigned short lds[36864];
    const int bid = blockIdx.x;
    const int mblk = bid & 31;
    const int head = bid >> 5;
    const int tid = threadIdx.x;
    const int lane = tid & 63;
    const int w = tid >> 6;
    const int l15 = lane & 15, quad = lane >> 4;

    f32x4 aq[2][4] = {}, ak[2][4] = {}, av[2][4] = {};
    const size_t abase0 = (size_t)mblk * 131072;
    const size_t bbase0 = (size_t)head * 65536;

    for (int kb = 0; kb < 16; ++kb) {
        __syncthreads();
        {
            const size_t ab = abase0 + (size_t)kb * 8192;
            const size_t bb = bbase0 + (size_t)kb * 4096;
#pragma unroll
            for (int j = 0; j < 4; ++j) {
                int seg = j * 256 + tid;
                gl_lds16(Xh + ab + seg * 8, &lds[seg * 8]);
                gl_lds16(Xl + ab + seg * 8, &lds[8192 + seg * 8]);
            }
#pragma unroll
            for (int j = 0; j < 2; ++j) {
                int seg = j * 256 + tid;
                gl_lds16(Wqh + bb + seg * 8, &lds[16384 + seg * 8]);
                gl_lds16(Wql + bb + seg * 8, &lds[20480 + seg * 8]);
                gl_lds16(Wkh + bb + seg * 8, &lds[24576 + seg * 8]);
                gl_lds16(Wkl + bb + seg * 8, &lds[28672 + seg * 8]);
                gl_lds16(Wvt + bb + seg * 8, &lds[32768 + seg * 8]);
            }
        }
        __syncthreads();

#pragma unroll
        for (int ksub = 0; ksub < 2; ++ksub) {
            bf16x8 ah[2], al8[2];
#pragma unroll
            for (int mt = 0; mt < 2; ++mt) {
                int row = w * 32 + mt * 16 + l15;
                int g = (ksub * 4 + quad) ^ (row & 7);
                ah[mt] = *(const bf16x8*)&lds[row * 64 + g * 8];
                al8[mt] = *(const bf16x8*)&lds[8192 + row * 64 + g * 8];
            }
#pragma unroll
            for (int nt = 0; nt < 4; ++nt) {
                int col = nt * 16 + l15;
                int o = col * 64 + ((ksub * 4 + quad) ^ (col & 7)) * 8;
                bf16x8 bqh = *(const bf16x8*)&lds[16384 + o];
                bf16x8 bql = *(const bf16x8*)&lds[20480 + o];
                bf16x8 bkh = *(const bf16x8*)&lds[24576 + o];
                bf16x8 bkl = *(const bf16x8*)&lds[28672 + o];
                bf16x8 bv = *(const bf16x8*)&lds[32768 + o];
#pragma unroll
                for (int mt = 0; mt < 2; ++mt) {
                    f32x4 a = aq[mt][nt];
                    a = MFMA(ah[mt], bqh, a);
                    a = MFMA(ah[mt], bql, a);
                    a = MFMA(al8[mt], bqh, a);
                    aq[mt][nt] = a;
                    f32x4 b = ak[mt][nt];
                    b = MFMA(ah[mt], bkh, b);
                    b = MFMA(ah[mt], bkl, b);
                    b = MFMA(al8[mt], bkh, b);
                    ak[mt][nt] = b;
                    av[mt][nt] = MFMA(ah[mt], bv, av[mt][nt]);
                }
            }
        }
    }

#pragma unroll
    for (int mt = 0; mt < 2; ++mt) {
        const int rbase = mblk * 128 + w * 32 + mt * 16 + quad * 4;
#pragma unroll
        for (int nt = 0; nt < 4; ++nt) {
            const int col = head * 64 + nt * 16 + l15;
#pragma unroll
            for (int r = 0; r < 4; ++r) {
                size_t a = (size_t)(rbase + r) * D_DIM + col;
                float vq = aq[mt][nt][r];
                unsigned short hq = f2bf(vq);
                Qh[a] = hq;
                Ql[a] = f2bf(vq - bf2f(hq));
                float vk = ak[mt][nt][r];
                unsigned short hk = f2bf(vk);
                Kh[a] = hk;
                Kl[a] = f2bf(vk - bf2f(hk));
            }
            ushort4 vp;
            vp.x = f2bf(av[mt][nt][0]);
            vp.y = f2bf(av[mt][nt][1]);
            vp.z = f2bf(av[mt][nt][2]);
            vp.w = f2bf(av[mt][nt][3]);
            *(ushort4*)(Vt + (size_t)col * (2 * S_LEN) + rbase) = vp;
        }
    }
}

// ---------------------------------------------------------------------------
// attn: flash attention, S^T = K.Q^T.  Round-13 = EXACT round-6 kernel
// (verified best: attn 95.5 us, total 237.1 us):
//  * XCD panel swizzle: qblk in HIGH bid bits (R5-measured FETCH -80%).
//  * defer-max (T13, THR=8 in exp2 domain).
//  * li via ones-MFMA.  NO setprio (R8: regression).  Plain __syncthreads
//    (R7 counted-vmcnt raced).  16 q/wave (32q closed: R10/R11/R12 all
//    lose -- the ~150-reg state can't reach >=12 waves/CU).
// 512-thread blocks (8 waves x 16 q-rows), 64-key chunks, double-buffered
// 24 KB staging x2 + 8x2 KB P = 64 KB LDS -> 2 blocks/CU, 16 waves/CU.
// grid: qblk(16) x dir(2) x head(16) = 512 blocks x 512 threads
// ---------------------------------------------------------------------------
__global__ __launch_bounds__(512, 4) void attn_kernel(const unsigned short* __restrict__ Qh_,
                                                      const unsigned short* __restrict__ Ql_,
                                                      const unsigned short* __restrict__ Kh_,
                                                      const unsigned short* __restrict__ Kl_,
                                                      const unsigned short* __restrict__ Vt_,
                                                      unsigned short* __restrict__ Oatt) {
    // shorts: buf0 Kh[0,4096) Kl[4096,8192) V[8192,12288); buf1 +12288; P 24576+w*1024
    __shared__ unsigned short lds[32768];
    const int bid = blockIdx.x;
    // XCD panel swizzle: low 5 bits = (dir,head) panel id; qblk = high bits.
    const int head = bid & 15;
    const int dir = (bid >> 4) & 1;
    const int qblk = bid >> 5;
    const int src_q = dir, src_kv = 1 - dir;

    const int tid = threadIdx.x;  // 0..511
    const int lane = tid & 63;
    const int w = tid >> 6;  // 0..7
    const int l15 = lane & 15, quad = lane >> 4;
    const int q0w = qblk * 128 + w * 16;

    const unsigned short* KhB0 = Kh_ + (size_t)(src_kv * S_LEN) * D_DIM + head * 64;
    const unsigned short* KlB0 = Kl_ + (size_t)(src_kv * S_LEN) * D_DIM + head * 64;
    const unsigned short* Vtp = Vt_ + (size_t)(head * 64) * (2 * S_LEN) + src_kv * S_LEN;

    const int i0 = tid;  // 512 threads cover the 512 8-short segments of each tile
    const int sr0 = i0 >> 3, sc0 = ((i0 & 7) ^ (sr0 & 7)) * 8;

    auto stage = [&](int k0, int boff) {
        const unsigned short* KhB = KhB0 + (size_t)k0 * D_DIM;
        const unsigned short* KlB = KlB0 + (size_t)k0 * D_DIM;
        const unsigned short* VB = Vtp + k0;
        gl_lds16(KhB + (size_t)sr0 * D_DIM + sc0, &lds[boff + i0 * 8]);
        gl_lds16(KlB + (size_t)sr0 * D_DIM + sc0, &lds[boff + 4096 + i0 * 8]);
        gl_lds16(VB + (size_t)sr0 * (2 * S_LEN) + sc0, &lds[boff + 8192 + i0 * 8]);
    };

    // Q fragments (B-operand): B[k=e][n=q], lane n=l15, k=quad*8+j (+c*32)
    bf16x8 qh[2], ql[2];
    {
        const size_t qrow = (size_t)(src_q * S_LEN + q0w + l15) * D_DIM + head * 64 + quad * 8;
#pragma unroll
        for (int c = 0; c < 2; ++c) {
            qh[c] = *(const bf16x8*)(Qh_ + qrow + c * 32);
            ql[c] = *(const bf16x8*)(Ql_ + qrow + c * 32);
        }
    }

    // ones A-fragment for the li row-sum MFMA (bf16 1.0 = 0x3F80)
    bf16x8 ones_;
#pragma unroll
    for (int i = 0; i < 8; ++i) ones_[i] = (short)0x3F80;

    f32x4 o[4] = {};  // out^T tiles over e-tiles; lane: q=l15, e=quad*4+r
    f32x4 li = {};    // denominator, replicated across rows; lane q=l15
    float mi = -1e30f;
    unsigned short* Pw = lds + 24576 + w * 1024;

    auto chunk = [&](int kb) {
        // S^T tiles: sa[kt], keys kt*16+quad*4+r, q = l15 (3-pass split-bf16)
        f32x4 sa[4];
#pragma unroll
        for (int kt = 0; kt < 4; ++kt) {
            const int row = kt * 16 + l15;
            const int s0 = (quad ^ (row & 7)) * 8;
            const int s1 = ((4 + quad) ^ (row & 7)) * 8;
            bf16x8 kh0 = *(const bf16x8*)&lds[kb + row * 64 + s0];
            bf16x8 kh1 = *(const bf16x8*)&lds[kb + row * 64 + s1];
            bf16x8 kl0 = *(const bf16x8*)&lds[kb + 4096 + row * 64 + s0];
            bf16x8 kl1 = *(const bf16x8*)&lds[kb + 4096 + row * 64 + s1];
            f32x4 a = {};
            a = MFMA(kh0, qh[0], a);
            a = MFMA(kh1, qh[1], a);
            a = MFMA(kl0, qh[0], a);
            a = MFMA(kl1, qh[1], a);
            a = MFMA(kh0, ql[0], a);
            a = MFMA(kh1, ql[1], a);
            sa[kt] = a;
        }

        // online softmax (exp2 domain), defer-max THR=8
        f32x4 t4 = __builtin_elementwise_max(__builtin_elementwise_max(sa[0], sa[1]),
                                             __builtin_elementwise_max(sa[2], sa[3]));
        float tm = fmaxf(fmaxf(t4[0], t4[1]), fmaxf(t4[2], t4[3]));
        tm = fmaxf(tm, __shfl_xor(tm, 16, 64));
        tm = fmaxf(tm, __shfl_xor(tm, 32, 64));
        if (__ballot(tm > mi + 8.f)) {  // rescale only on >8 max growth (T13)
            float mn = fmaxf(mi, tm);
            float al = exp2f(mi - mn);
            mi = mn;
            const f32x4 alv = {al, al, al, al};
            li *= alv;
#pragma unroll
            for (int et = 0; et < 4; ++et) o[et] *= alv;
        }
        const f32x4 mnv = {mi, mi, mi, mi};
#pragma unroll
        for (int kt = 0; kt < 4; ++kt) {
            f32x4 p = sa[kt] - mnv;
#pragma unroll
            for (int r = 0; r < 4; ++r) p[r] = exp2f(p[r]);
            uint2 pk;
            pk.x = pack_bf16(p[0], p[1]);
            pk.y = pack_bf16(p[2], p[3]);
            int g = (kt * 2 + (quad >> 1)) ^ (l15 & 7);
            *(uint2*)&Pw[l15 * 64 + g * 8 + (quad & 1) * 4] = pk;
        }

        // PV: out^T = V^T . P^T  (A = staged V from LDS, B = P^T from LDS);
        // li accumulated by an extra MFMA with ones A-operand.
#pragma unroll
        for (int c = 0; c < 2; ++c) {
            bf16x8 pf = *(const bf16x8*)&Pw[l15 * 64 + (((c * 4 + quad) ^ (l15 & 7)) * 8)];
            li = MFMA(ones_, pf, li);
#pragma unroll
            for (int et = 0; et < 4; ++et) {
                const int row = et * 16 + l15;
                const int sl = ((c * 4 + quad) ^ (row & 7)) * 8;
                bf16x8 vf = *(const bf16x8*)&lds[kb + 8192 + row * 64 + sl];
                o[et] = MFMA(vf, pf, o[et]);
            }
        }
    };

    stage(0, 0);
#pragma unroll 1
    for (int kd = 0; kd < 32; kd += 2) {
        __syncthreads();  // buf0 (chunk kd) ready
        if (kd + 1 < 32) stage((kd + 1) * 64, 12288);
        chunk(0);
        __syncthreads();  // buf1 (chunk kd+1) ready
        if (kd + 2 < 32) stage((kd + 2) * 64, 0);
        chunk(12288);
    }

    // epilogue: li holds the full key-sum (replicated across rows);
    // normalize, store to TILED Oatt.  rowit = qblk*8 + w (bijection kept).
    const size_t obase = (size_t)(dir * 16 + head) * 131072 + (size_t)l15 * 8192;
    {
        float rl = __builtin_amdgcn_rcpf(li[0]);
        const int rowit = qblk * 8 + w;
#pragma unroll
        for (int et = 0; et < 4; ++et) {
            int g = ((et * 2 + (quad >> 1)) ^ (rowit & 7)) & 7;
            ushort4 pk;
            pk.x = f2bf(o[et][0] * rl);
            pk.y = f2bf(o[et][1] * rl);
            pk.z = f2bf(o[et][2] * rl);
            pk.w = f2bf(o[et][3] * rl);
            *(ushort4*)(Oatt + obase + (size_t)rowit * 64 + g * 8 + (quad & 1) * 4) = pk;
        }
    }
}

// ---------------------------------------------------------------------------
// oproj: out = view @ Wo, staged-LDS GEMM, double-buffered prefetch.
// XCD relabel: mblk in LOW bits -> A-panel (Oatt) sharers at stride-32 bids
// = one XCD; per-XCD working set (4 A-panels + all B) ~3 MB = L2-resident.
// grid: nblk(16) x mblk(32) = 512 blocks
// ---------------------------------------------------------------------------
__global__ __launch_bounds__(256) void oproj(const unsigned short* __restrict__ Oatt,
                                             const unsigned short* __restrict__ Wot,
                                             float* __restrict__ out) {
    __shared__ unsigned short lds[24576];  // buf: A 8192 + B 4096; x2
    const int bid = blockIdx.x;
    const int mblk = bid & 31;
    const int nblk = bid >> 5;
    const int tid = threadIdx.x;
    const int lane = tid & 63, w = tid >> 6, l15 = lane & 15, quad = lane >> 4;

    f32x4 acc[2][4] = {};
    const size_t abase = (size_t)mblk * 131072;
    const size_t bbase = (size_t)nblk * 65536;

    auto ostage = [&](int kb, int boff) {
#pragma unroll
        for (int j = 0; j < 4; ++j) {
            int seg = j * 256 + tid;
            gl_lds16(Oatt + abase + (size_t)kb * 8192 + seg * 8, &lds[boff + seg * 8]);
        }
#pragma unroll
        for (int j = 0; j < 2; ++j) {
            int seg = j * 256 + tid;
            gl_lds16(Wot + bbase + (size_t)kb * 4096 + seg * 8, &lds[boff + 8192 + seg * 8]);
        }
    };

    auto compute = [&](int boff) {
#pragma unroll
        for (int ksub = 0; ksub < 2; ++ksub) {
            bf16x8 a[2];
#pragma unroll
            for (int mt = 0; mt < 2; ++mt) {
                int row = w * 32 + mt * 16 + l15;
                a[mt] =
                    *(const bf16x8*)&lds[boff + row * 64 + (((ksub * 4 + quad) ^ (row & 7)) * 8)];
            }
#pragma unroll
            for (int nt = 0; nt < 4; ++nt) {
                int col = nt * 16 + l15;
                bf16x8 b = *(const bf16x8*)&lds[boff + 8192 + col * 64 +
                                                (((ksub * 4 + quad) ^ (col & 7)) * 8)];
#pragma unroll
                for (int mt = 0; mt < 2; ++mt) acc[mt][nt] = MFMA(a[mt], b, acc[mt][nt]);
            }
        }
    };

    ostage(0, 0);
#pragma unroll 1
    for (int kb = 0; kb < 16; kb += 2) {
        __syncthreads();
        if (kb + 1 < 16) ostage(kb + 1, 12288);
        compute(0);
        __syncthreads();
        if (kb + 2 < 16) ostage(kb + 2, 0);
        compute(12288);
    }

#pragma unroll
    for (int mt = 0; mt < 2; ++mt) {
        const int rbase = mblk * 128 + w * 32 + mt * 16 + quad * 4;
#pragma unroll
        for (int nt = 0; nt < 4; ++nt)
#pragma unroll
            for (int r = 0; r < 4; ++r)
                out[(size_t)(rbase + r) * D_DIM + nblk * 64 + nt * 16 + l15] = acc[mt][nt][r];
    }
}

// ---------------------------------------------------------------------------
extern "C" void kernel_launch(void* const* d_in, const int* in_sizes, int n_in, void* d_out,
                              int out_size, void* d_ws, size_t ws_size, hipStream_t stream) {
    const float* GLO = (const float*)d_in[0];
    const float* LOC = (const float*)d_in[1];
    const float* Wq = (const float*)d_in[2];
    const float* Wk = (const float*)d_in[3];
    const float* Wv = (const float*)d_in[4];
    const float* Wo = (const float*)d_in[5];
    float* out = (float*)d_out;

    unsigned short* ws = (unsigned short*)d_ws;
    unsigned short* Xh = ws + 0;
    unsigned short* Xl = ws + 4194304;
    unsigned short* Wqh = ws + 8388608;
    unsigned short* Wql = ws + 9437184;
    unsigned short* Wkh = ws + 10485760;
    unsigned short* Wkl = ws + 11534336;
    unsigned short* Wvt = ws + 12582912;
    unsigned short* Wot = ws + 13631488;
    unsigned short* Qh = ws + 14680064;
    unsigned short* Ql = ws + 18874368;
    unsigned short* Kh = ws + 23068672;
    unsigned short* Kl = ws + 27262976;
    unsigned short* Vt = ws + 31457280;
    unsigned short* Oatt = ws + 35651584;

    prep<<<4096, 256, 0, stream>>>(GLO, LOC, Wq, Wk, Wv, Wo, Xh, Xl, Wqh, Wql, Wkh, Wkl, Wvt, Wot);
    qkv_proj<<<512, 256, 0, stream>>>(Xh, Xl, Wqh, Wql, Wkh, Wkl, Wvt, Qh, Ql, Kh, Kl, Vt);
    attn_kernel<<<512, 512, 0, stream>>>(Qh, Ql, Kh, Kl, Vt, Oatt);
    oproj<<<512, 256, 0, stream>>>(Oatt, Wot, out);
}